// Round 3
// baseline (314.075 us; speedup 1.0000x reference)
//
#include <hip/hip_runtime.h>

#define B_ 16
#define S_ 20
#define L_ 64
#define T_ 1280
#define H_ 768
#define NITEMS 50000
#define TEMP 0.05f
#define EPSN 1e-8f

#define BM 320
#define BN 64
#define BK 32
#define NKT (H_ / BK)  // 24

typedef __attribute__((ext_vector_type(8))) short short8;
typedef __attribute__((ext_vector_type(4))) short short4v;
typedef __attribute__((ext_vector_type(4))) float f32x4;

// float -> bf16 (round-to-nearest-even)
__device__ __forceinline__ unsigned short f2bf(float f) {
    unsigned int u = __float_as_uint(f);
    u = u + 0x7FFFu + ((u >> 16) & 1u);
    return (unsigned short)(u >> 16);
}

// async global->LDS, 16B per lane. LDS dest must be wave-uniform base + lane*16.
typedef __attribute__((address_space(3))) void lds_void;
typedef const __attribute__((address_space(1))) void gbl_void;
__device__ __forceinline__ void load_lds16(const void* g, void* l) {
    __builtin_amdgcn_global_load_lds((gbl_void*)g, (lds_void*)l, 16, 0, 0);
}

// ---------------------------------------------------------------------------
// Kernel 1: per-(b,s) nan-mean pool, normalize, fold 1/(pn*TEMP), write bf16.
// Output slot-swizzle: logical 16B-slot q of row r stored at q ^ ((r>>1)&3)
// within each 32-col chunk (gemm stages ws linearly via global_load_lds and
// de-swizzles at fragment read; measured conflict-free in round 2).
// ---------------------------------------------------------------------------
__global__ __launch_bounds__(384) void pool_kernel(const float* __restrict__ hidden,
                                                   const int* __restrict__ pos,
                                                   unsigned short* __restrict__ A,
                                                   int* __restrict__ valid) {
    const int row = blockIdx.x;  // 0..319
    const int b = row / S_, s = row % S_;
    const int tid = threadIdx.x;  // 0..383; thread owns cols 2*tid, 2*tid+1

    __shared__ float wgt[L_];
    __shared__ int cntS;
    __shared__ float red[6];

    const int* pbase = pos + b * T_ + s * L_;
    if (tid < L_) {  // exactly wave 0
        const int match = (pbase[tid] == s + 1) ? 1 : 0;
        unsigned long long bal = __ballot(match);
        wgt[tid] = match ? 1.0f : 0.0f;
        if (tid == 0) cntS = (int)__popcll(bal);
    }
    __syncthreads();

    const int cnt = cntS;
    const float inv = 1.0f / (float)(cnt > 0 ? cnt : 1);
    const float* hbase = hidden + ((size_t)b * T_ + (size_t)s * L_) * H_ + tid * 2;

    float a0 = 0.f, a1 = 0.f;
#pragma unroll 8
    for (int t = 0; t < L_; ++t) {
        const float w = wgt[t];
        const float2 v = *reinterpret_cast<const float2*>(hbase + (size_t)t * H_);
        a0 += w * v.x; a1 += w * v.y;
    }
    a0 *= inv; a1 *= inv;

    // sum of squares over 768 cols (6 waves)
    float ss = a0 * a0 + a1 * a1;
#pragma unroll
    for (int off = 32; off; off >>= 1) ss += __shfl_xor(ss, off, 64);
    const int wave = tid >> 6, lane = tid & 63;
    if (lane == 0) red[wave] = ss;
    __syncthreads();
    const float tot = red[0] + red[1] + red[2] + red[3] + red[4] + red[5];
    const float scale = 1.0f / (fmaxf(sqrtf(tot), EPSN) * TEMP);

    // swizzled store: c0 = 2*tid; chunk = c0>>5; logical slot (c0>>3)&3
    const int chunk = tid >> 4;
    const int cSlot = (tid >> 2) & 3;
    const int phys = cSlot ^ ((row >> 1) & 3);
    unsigned short r0 = f2bf(a0 * scale);
    unsigned short r1 = f2bf(a1 * scale);
    unsigned int pk = (unsigned int)r0 | ((unsigned int)r1 << 16);
    *reinterpret_cast<unsigned int*>(A + (size_t)row * H_ + chunk * 32 + phys * 8 +
                                     ((tid * 2) & 7)) = pk;
    if (tid == 0) valid[row] = (cnt > 0) ? 1 : 0;
}

// ---------------------------------------------------------------------------
// Kernel 2: full-M GEMM, occupancy-fixed.
// Round-2 failure analysis: acc[5][8] = 160 VGPRs + 116 arch = 276 unified
// VGPRs/wave -> 1 wave/SIMD (Occupancy 14%): ZERO latency hiding, so every
// pipeline variant measured ~90us. Fix: BN=64 -> acc[5][4] = 80 VGPRs,
// total ~150 <= 170 -> 3 waves/SIMD; grid 782 = 3.05 blocks/CU (balanced,
// was 1.53); LDS 49.5 KB -> 3 blocks/CU. Same counted-vmcnt template:
//   [A] issue B(kt+1)->regs (2x dwordx4)
//   [B] vmcnt(2): A(kt) dma done, B(kt+1) in flight
//   [C] raw s_barrier + fences
//   [D] issue A(kt+1) gload_lds -> As[cur^1]
//   [E] ds_read frags (dual-swizzled, conflict-free) + 20 MFMA (setprio 1)
//   [F] consume B regs: en partials, cvt, swizzled ds_write -> Bs[cur^1]
//   [G] lgkmcnt(0)
// ---------------------------------------------------------------------------
__global__ __launch_bounds__(256, 3) void gemm_kernel(const float* __restrict__ emb,
                                                      const unsigned short* __restrict__ A,
                                                      const int* __restrict__ valid,
                                                      float* __restrict__ out) {
    const int n0 = blockIdx.x * BN;
    const int tid = threadIdx.x;
    const int wave = tid >> 6, lane = tid & 63, quad = lane >> 4, lq = lane & 15;

    __shared__ alignas(16) short As[2][BM * BK];  // 2 x 20 KB bf16 (swizzled content)
    __shared__ alignas(16) short Bs[2][BN * BK];  // 2 x  4 KB bf16 (swizzled slots)
    __shared__ float sEn[BN];
    __shared__ int sMask[B_];

    // per-session validity bitmask (20 bits)
    if (tid < B_) {
        int m = 0;
        for (int s = 0; s < S_; ++s) m |= (valid[tid * S_ + s] ? 1 : 0) << s;
        sMask[tid] = m;
    }

    // --- staging geometry ---
    // A: 5 gload_lds issues; issue i covers row tid/4 + i*64, phys slot tid&3
    // (ws is pre-swizzled by pool_kernel, so the copy stays linear).
    const unsigned short* aSrc = A + (size_t)(tid >> 2) * H_ + (tid & 3) * 8;
    // B: thread owns n-row tid>>2 (0..63), 8 fp32 at cols (tid&3)*8 (+k0).
    const int brLoc = tid >> 2;
    int brGlb = n0 + brLoc;
    if (brGlb > NITEMS - 1) brGlb = NITEMS - 1;  // clamp: OOB cols computed, never stored
    const float* bSrc = emb + (size_t)brGlb * H_ + (tid & 3) * 8;
    // swizzled LDS write offset (shorts): logical slot tid&3 at phys q^((brLoc>>1)&3)
    const int bw = brLoc * BK + (((tid & 3) ^ ((brLoc >> 1) & 3)) * 8);

    float rowSq = 0.f;

    // --- prologue: stage tile 0 (drained once; steady state never drains) ---
    {
        const float4 v0 = *reinterpret_cast<const float4*>(bSrc);
        const float4 v1 = *reinterpret_cast<const float4*>(bSrc + 4);
#pragma unroll
        for (int i = 0; i < 5; ++i)
            load_lds16(aSrc + i * 64 * H_, (char*)(&As[0][0]) + tid * 16 + i * 4096);
        rowSq += v0.x * v0.x + v0.y * v0.y + v0.z * v0.z + v0.w * v0.w;
        rowSq += v1.x * v1.x + v1.y * v1.y + v1.z * v1.z + v1.w * v1.w;
        short8 pk;
        pk[0] = (short)f2bf(v0.x); pk[1] = (short)f2bf(v0.y);
        pk[2] = (short)f2bf(v0.z); pk[3] = (short)f2bf(v0.w);
        pk[4] = (short)f2bf(v1.x); pk[5] = (short)f2bf(v1.y);
        pk[6] = (short)f2bf(v1.z); pk[7] = (short)f2bf(v1.w);
        *reinterpret_cast<short8*>(&Bs[0][bw]) = pk;
    }
    asm volatile("s_waitcnt vmcnt(0)" ::: "memory");
    __syncthreads();

    f32x4 acc[5][4];
#pragma unroll
    for (int i = 0; i < 5; ++i)
#pragma unroll
        for (int j = 0; j < 4; ++j) acc[i][j] = (f32x4)0.f;

    const int fswz = (lq >> 1) & 3;  // frag-read slot swizzle (same for A and B)
    int cur = 0;
    for (int kt = 0; kt < NKT; ++kt) {
        const bool more = (kt + 1 < NKT);
        // [A] next B tile -> regs
        float4 v0, v1;
        if (more) {
            const int k0 = (kt + 1) * BK;
            v0 = *reinterpret_cast<const float4*>(bSrc + k0);
            v1 = *reinterpret_cast<const float4*>(bSrc + k0 + 4);
        }
        // [B] wait A(kt) dma landed; keep the 2 B loads in flight
        if (more) asm volatile("s_waitcnt vmcnt(2)" ::: "memory");
        else      asm volatile("s_waitcnt vmcnt(0)" ::: "memory");
        // [C] raw barrier; fence against code motion
        __builtin_amdgcn_s_barrier();
        __builtin_amdgcn_sched_barrier(0);
        asm volatile("" ::: "memory");
        // [D] next A tile -> other LDS buffer (stays in flight across next barrier)
        if (more) {
            const int k0 = (kt + 1) * BK;
#pragma unroll
            for (int i = 0; i < 5; ++i)
                load_lds16(aSrc + k0 + i * 64 * H_,
                           (char*)(&As[cur ^ 1][0]) + tid * 16 + i * 4096);
        }
        // [E] fragments + MFMA
        short8 bF[4];
#pragma unroll
        for (int nf = 0; nf < 4; ++nf) {
            const int rB = nf * 16 + lq;
            bF[nf] = *reinterpret_cast<const short8*>(
                &Bs[cur][rB * BK + ((quad ^ fswz) * 8)]);
        }
        __builtin_amdgcn_s_setprio(1);
#pragma unroll
        for (int mf = 0; mf < 5; ++mf) {
            const int rA = wave * 80 + mf * 16 + lq;
            const short8 aF = *reinterpret_cast<const short8*>(
                &As[cur][rA * BK + ((quad ^ fswz) * 8)]);
#pragma unroll
            for (int nf = 0; nf < 4; ++nf)
                acc[mf][nf] =
                    __builtin_amdgcn_mfma_f32_16x16x32_bf16(aF, bF[nf], acc[mf][nf], 0, 0, 0);
        }
        __builtin_amdgcn_s_setprio(0);
        // [F] consume B regs: en partials + cvt + swizzled ds_write
        if (more) {
            rowSq += v0.x * v0.x + v0.y * v0.y + v0.z * v0.z + v0.w * v0.w;
            rowSq += v1.x * v1.x + v1.y * v1.y + v1.z * v1.z + v1.w * v1.w;
            short8 pk;
            pk[0] = (short)f2bf(v0.x); pk[1] = (short)f2bf(v0.y);
            pk[2] = (short)f2bf(v0.z); pk[3] = (short)f2bf(v0.w);
            pk[4] = (short)f2bf(v1.x); pk[5] = (short)f2bf(v1.y);
            pk[6] = (short)f2bf(v1.z); pk[7] = (short)f2bf(v1.w);
            *reinterpret_cast<short8*>(&Bs[cur ^ 1][bw]) = pk;
        }
        // [G] ds_writes visible before next barrier
        asm volatile("s_waitcnt lgkmcnt(0)" ::: "memory");
        cur ^= 1;
    }

    // finalize en (4 threads per row, accumulated in regs during staging)
    rowSq += __shfl_xor(rowSq, 1, 64);
    rowSq += __shfl_xor(rowSq, 2, 64);
    if (!(tid & 3)) sEn[brLoc] = fmaxf(sqrtf(rowSq), EPSN);
    __syncthreads();

    // epilogue: wave w owns sessions 4w..4w+3 (80 rows = exactly 4 sessions).
    // C/D layout: col = lane&15 (n), row = quad*4+e (m).
#pragma unroll
    for (int nf = 0; nf < 4; ++nf) {
        const int ncol = nf * 16 + lq;
        const int n = n0 + ncol;
        const float inv_en = 1.0f / sEn[ncol];
#pragma unroll
        for (int bl = 0; bl < 4; ++bl) {
            const int bb = wave * 4 + bl;
            const int msk = sMask[bb];
            const int rLo = bl * S_;  // local row base within this wave's 80-row slice
            float lm = -__builtin_inff();
            const int mfLo = rLo >> 4;
            const int mfHi = (rLo + S_ - 1) >> 4;
#pragma unroll
            for (int mf = mfLo; mf <= mfHi; ++mf)
#pragma unroll
                for (int e = 0; e < 4; ++e) {
                    const int r = mf * 16 + quad * 4 + e;
                    const unsigned off = (unsigned)(r - rLo);
                    const bool ok = (off < (unsigned)S_) && ((msk >> off) & 1);
                    lm = ok ? fmaxf(lm, acc[mf][nf][e]) : lm;
                }
            lm = fmaxf(lm, __shfl_xor(lm, 16, 64));
            lm = fmaxf(lm, __shfl_xor(lm, 32, 64));
            if (quad == 0 && n < NITEMS)
                out[(size_t)bb * NITEMS + n] = lm * inv_en;
        }
    }
}

extern "C" void kernel_launch(void* const* d_in, const int* in_sizes, int n_in,
                              void* d_out, int out_size, void* d_ws, size_t ws_size,
                              hipStream_t stream) {
    const float* hidden = (const float*)d_in[0];   // [16,1280,768] f32
    const float* emb    = (const float*)d_in[1];   // [50000,768] f32
    const int*   pos    = (const int*)d_in[3];     // [16,1280] i32
    float* out = (float*)d_out;                    // [16,50000] f32

    unsigned short* Abf = (unsigned short*)d_ws;               // 320*768 bf16 (swizzled)
    int* valid = (int*)((char*)d_ws + (size_t)320 * 768 * 2);  // 320 ints

    pool_kernel<<<dim3(320), dim3(384), 0, stream>>>(hidden, pos, Abf, valid);
    gemm_kernel<<<dim3((NITEMS + BN - 1) / BN), dim3(256), 0, stream>>>(emb, Abf, valid, out);
}